// Round 15
// baseline (478.795 us; speedup 1.0000x reference)
//
#include <hip/hip_runtime.h>
#include <math.h>

#define NN 100000
#define NE 1600000
#define EPSF 1e-5f
#define NB 391          // buckets of 256 nodes
#define BKN 256
#define CAP 4864        // fixed bucket capacity (mean 4092, sigma 64 -> +12 sigma)
#define CHA 4096        // edges per block in bucket scatter

typedef unsigned short u16;
typedef unsigned int u32;
typedef __attribute__((ext_vector_type(8))) short bf16x8;   // MFMA A/B frag (4 VGPRs)
typedef __attribute__((ext_vector_type(4))) float f32x4;    // MFMA C/D frag
typedef __attribute__((ext_vector_type(8))) unsigned short u16x8;

__device__ __forceinline__ u16 f2bf(float f) {
    u32 u = __float_as_uint(f);
    u32 r = (u + 0x7fffu + ((u >> 16) & 1u)) >> 16;   // RNE
    return (u16)r;
}
__device__ __forceinline__ float bf_lo(u32 u) { return __uint_as_float(u << 16); }
__device__ __forceinline__ float bf_hi(u32 u) { return __uint_as_float(u & 0xffff0000u); }

// ---------------- misc ----------------
__global__ void k_zero_ints(int* p, int n) {
    int i = blockIdx.x * 256 + threadIdx.x;
    if (i < n) p[i] = 0;
}

// ---------------- weight pre-transpose: Wt[c][k] bf16 (once per launch) ----------------
__global__ __launch_bounds__(256) void k_prept(const float* __restrict__ W0,
                                               const float* __restrict__ W1,
                                               const float* __restrict__ W2,
                                               u16* __restrict__ wt0,
                                               u16* __restrict__ wt1,
                                               u16* __restrict__ wt2) {
    int b = blockIdx.x, t = threadIdx.x;
    if (b < 8) {
        for (int idx = t; idx < 16 * 128; idx += 256) {
            int k = b * 16 + (idx >> 7), c = idx & 127;
            wt0[c * 128 + k] = f2bf(W0[k * 128 + c]);
        }
    } else if (b < 16) {
        for (int idx = t; idx < 16 * 128; idx += 256) {
            int k = (b - 8) * 16 + (idx >> 7), c = idx & 127;
            wt1[c * 128 + k] = f2bf(W1[k * 128 + c]);
        }
    } else {
        for (int idx = t; idx < 16 * 64; idx += 256) {
            int k = (b - 16) * 16 + (idx >> 6), c = idx & 63;
            wt2[c * 128 + k] = f2bf(c < 40 ? W2[k * 40 + c] : 0.f);
        }
    }
}

// ---------------- CSR build pass A: scatter edges into fixed-capacity buckets ----------------
__global__ __launch_bounds__(256) void k_bscatter(const int* __restrict__ src,
                                                  const int* __restrict__ dst,
                                                  int* __restrict__ gcur,
                                                  u32* __restrict__ bkt) {
    __shared__ int hist[NB];
    __shared__ int base[NB];
    int t = threadIdx.x;
    long e0 = (long)blockIdx.x * CHA;
    for (int i = t; i < NB; i += 256) hist[i] = 0;
    __syncthreads();
#pragma unroll
    for (int i = 0; i < CHA / 256; i++) {
        long e = e0 + i * 256 + t;
        if (e < NE) atomicAdd(&hist[dst[e] >> 8], 1);
    }
    __syncthreads();
    for (int i = t; i < NB; i += 256)
        base[i] = i * CAP + atomicAdd(&gcur[i], hist[i]);
    __syncthreads();
    for (int i = t; i < NB; i += 256) hist[i] = 0;
    __syncthreads();
#pragma unroll
    for (int i = 0; i < CHA / 256; i++) {
        long e = e0 + i * 256 + t;
        if (e < NE) {
            int d = dst[e];
            int s = src[e];
            int b = d >> 8;
            int r = atomicAdd(&hist[b], 1);
            bkt[base[b] + r] = (u32)s | ((u32)(d & 255) << 17);
        }
    }
}

// ---------------- CSR build pass B (per-bucket hist+scan+fill; rsd=(start<<8)|deg; dinv) ----------------
__global__ __launch_bounds__(BKN) void k_csr(const u32* __restrict__ bkt,
                                             const int* __restrict__ gcur,
                                             u32* __restrict__ rsd,
                                             int* __restrict__ csr,
                                             float* __restrict__ dinv) {
    __shared__ int cnt[BKN];
    __shared__ int tmp[BKN];
    __shared__ int cur[BKN];
    int t = threadIdx.x, b = blockIdx.x;
    int ebase = b * CAP;
    int m = gcur[b];
    cnt[t] = 0;
    __syncthreads();
    for (int i = t; i < m; i += BKN)
        atomicAdd(&cnt[(bkt[ebase + i] >> 17) & 255], 1);
    __syncthreads();
    int v = cnt[t];
    tmp[t] = v;
    __syncthreads();
    for (int o = 1; o < BKN; o <<= 1) {
        int u = (t >= o) ? tmp[t - o] : 0;
        __syncthreads();
        tmp[t] += u;
        __syncthreads();
    }
    int excl = tmp[t] - v;
    int node = b * BKN + t;
    if (node < NN) {
        rsd[node] = ((u32)(ebase + excl) << 8) | (u32)v;
        dinv[node] = rsqrtf((float)(v + 1));
    }
    cur[t] = ebase + excl;
    __syncthreads();
    for (int i = t; i < m; i += BKN) {
        u32 p = bkt[ebase + i];
        int pos = atomicAdd(&cur[(p >> 17) & 255], 1);
        csr[pos] = (int)(p & 0x1FFFFu);
    }
}

// ---------------- MFMA GEMM (layer0): fp32 X [n,128] @ Wt -> bf16 [n,128] ----------------
__global__ __launch_bounds__(256) void k_gemm128m_f0(const float* __restrict__ X,
                                                     const u16* __restrict__ WtG,
                                                     u16* __restrict__ Y, int n) {
    __shared__ u16 Xl[128][136];   // +8 pad
    __shared__ u16 Wt[128][136];   // Wt[col][k]
    int t = threadIdx.x;
    int row0 = blockIdx.x * 128;

#pragma unroll
    for (int i = 0; i < 16; i++) {
        int idx = t + i * 256;
        int r = idx >> 5, q = idx & 31;
        int gr = row0 + r;
        float4 v = make_float4(0.f, 0.f, 0.f, 0.f);
        if (gr < n) v = reinterpret_cast<const float4*>(X + (size_t)gr * 128)[q];
        ushort4 o;
        o.x = f2bf(v.x); o.y = f2bf(v.y); o.z = f2bf(v.z); o.w = f2bf(v.w);
        *reinterpret_cast<ushort4*>(&Xl[r][q * 4]) = o;
    }
#pragma unroll
    for (int i = 0; i < 8; i++) {
        int idx = t + i * 256;
        int r = idx >> 4, q = idx & 15;
        *reinterpret_cast<u16x8*>(&Wt[r][q * 8]) =
            *reinterpret_cast<const u16x8*>(&WtG[r * 128 + q * 8]);
    }
    __syncthreads();

    int lane = t & 63, w = t >> 6;
    int wr = (w >> 1) * 64, wc = (w & 1) * 64;
    int fr = lane & 15;
    int fs = (lane >> 4) * 8;
    f32x4 acc[4][4] = {};
#pragma unroll
    for (int ks = 0; ks < 4; ks++) {
        bf16x8 a[4], b[4];
#pragma unroll
        for (int m = 0; m < 4; m++)
            a[m] = *reinterpret_cast<const bf16x8*>(&Xl[wr + m * 16 + fr][ks * 32 + fs]);
#pragma unroll
        for (int c = 0; c < 4; c++)
            b[c] = *reinterpret_cast<const bf16x8*>(&Wt[wc + c * 16 + fr][ks * 32 + fs]);
#pragma unroll
        for (int m = 0; m < 4; m++)
#pragma unroll
            for (int c = 0; c < 4; c++)
                acc[m][c] = __builtin_amdgcn_mfma_f32_16x16x32_bf16(a[m], b[c], acc[m][c], 0, 0, 0);
    }

    int crow = (lane >> 4) * 4, ccol = lane & 15;
#pragma unroll
    for (int m = 0; m < 4; m++) {
#pragma unroll
        for (int c = 0; c < 4; c++) {
#pragma unroll
            for (int rg = 0; rg < 4; rg++) {
                int grow = row0 + wr + m * 16 + crow + rg;
                if (grow < n)
                    Y[(size_t)grow * 128 + wc + c * 16 + ccol] = f2bf(acc[m][c][rg]);
            }
        }
    }
}

// ---------------- MFMA GEMM (layer1): bf16-packed X + fused BN+ReLU -> bf16 [n,128] ----------------
__global__ __launch_bounds__(256) void k_gemm128m_b1(const u32* __restrict__ Xb,
                                                     const u16* __restrict__ WtG,
                                                     u16* __restrict__ Y, int n,
                                                     const float* __restrict__ stats,
                                                     const float* __restrict__ g,
                                                     const float* __restrict__ be) {
    __shared__ u16 Xl[128][136];
    __shared__ u16 Wt[128][136];
    __shared__ float ssc[128], ssh[128];
    int t = threadIdx.x;
    int row0 = blockIdx.x * 128;

    if (t < 128) {
        float mu = stats[t] * (1.0f / NN);
        float var = stats[128 + t] * (1.0f / NN) - mu * mu;
        float sc = rsqrtf(var + EPSF) * g[t];
        ssc[t] = sc;
        ssh[t] = be[t] - mu * sc;
    }
    __syncthreads();

#pragma unroll
    for (int i = 0; i < 8; i++) {
        int idx = t + i * 256;
        int r = idx >> 4, q = idx & 15;
        int gr = row0 + r;
        uint4 vv = make_uint4(0u, 0u, 0u, 0u);
        if (gr < n) vv = reinterpret_cast<const uint4*>(Xb + (size_t)gr * 64)[q];
        float f[8] = { bf_lo(vv.x), bf_hi(vv.x), bf_lo(vv.y), bf_hi(vv.y),
                       bf_lo(vv.z), bf_hi(vv.z), bf_lo(vv.w), bf_hi(vv.w) };
        u16x8 o;
#pragma unroll
        for (int e = 0; e < 8; e++) {
            int fi = q * 8 + e;
            float x = fmaxf(fmaf(f[e], ssc[fi], ssh[fi]), 0.f);
            o[e] = f2bf(x);
        }
        *reinterpret_cast<u16x8*>(&Xl[r][q * 8]) = o;
    }
#pragma unroll
    for (int i = 0; i < 8; i++) {
        int idx = t + i * 256;
        int r = idx >> 4, q = idx & 15;
        *reinterpret_cast<u16x8*>(&Wt[r][q * 8]) =
            *reinterpret_cast<const u16x8*>(&WtG[r * 128 + q * 8]);
    }
    __syncthreads();

    int lane = t & 63, w = t >> 6;
    int wr = (w >> 1) * 64, wc = (w & 1) * 64;
    int fr = lane & 15;
    int fs = (lane >> 4) * 8;
    f32x4 acc[4][4] = {};
#pragma unroll
    for (int ks = 0; ks < 4; ks++) {
        bf16x8 a[4], b[4];
#pragma unroll
        for (int m = 0; m < 4; m++)
            a[m] = *reinterpret_cast<const bf16x8*>(&Xl[wr + m * 16 + fr][ks * 32 + fs]);
#pragma unroll
        for (int c = 0; c < 4; c++)
            b[c] = *reinterpret_cast<const bf16x8*>(&Wt[wc + c * 16 + fr][ks * 32 + fs]);
#pragma unroll
        for (int m = 0; m < 4; m++)
#pragma unroll
            for (int c = 0; c < 4; c++)
                acc[m][c] = __builtin_amdgcn_mfma_f32_16x16x32_bf16(a[m], b[c], acc[m][c], 0, 0, 0);
    }

    int crow = (lane >> 4) * 4, ccol = lane & 15;
#pragma unroll
    for (int m = 0; m < 4; m++) {
#pragma unroll
        for (int c = 0; c < 4; c++) {
#pragma unroll
            for (int rg = 0; rg < 4; rg++) {
                int grow = row0 + wr + m * 16 + crow + rg;
                if (grow < n)
                    Y[(size_t)grow * 128 + wc + c * 16 + ccol] = f2bf(acc[m][c][rg]);
            }
        }
    }
}

// ---------------- MFMA GEMM (layer2): bf16-packed X + BN+ReLU -> bf16 [n,64] (40 valid) ----------------
__global__ __launch_bounds__(256) void k_gemm40m(const u32* __restrict__ Xb,
                                                 const u16* __restrict__ WtG,
                                                 u16* __restrict__ Y, int n,
                                                 const float* __restrict__ stats,
                                                 const float* __restrict__ g,
                                                 const float* __restrict__ be) {
    __shared__ u16 Xl[128][136];
    __shared__ u16 Wt[64][136];
    __shared__ float ssc[128], ssh[128];
    int t = threadIdx.x;
    int row0 = blockIdx.x * 128;

    if (t < 128) {
        float mu = stats[t] * (1.0f / NN);
        float var = stats[128 + t] * (1.0f / NN) - mu * mu;
        float sc = rsqrtf(var + EPSF) * g[t];
        ssc[t] = sc;
        ssh[t] = be[t] - mu * sc;
    }
    __syncthreads();

#pragma unroll
    for (int i = 0; i < 8; i++) {
        int idx = t + i * 256;
        int r = idx >> 4, q = idx & 15;
        int gr = row0 + r;
        uint4 vv = make_uint4(0u, 0u, 0u, 0u);
        if (gr < n) vv = reinterpret_cast<const uint4*>(Xb + (size_t)gr * 64)[q];
        float f[8] = { bf_lo(vv.x), bf_hi(vv.x), bf_lo(vv.y), bf_hi(vv.y),
                       bf_lo(vv.z), bf_hi(vv.z), bf_lo(vv.w), bf_hi(vv.w) };
        u16x8 o;
#pragma unroll
        for (int e = 0; e < 8; e++) {
            int fi = q * 8 + e;
            float x = fmaxf(fmaf(f[e], ssc[fi], ssh[fi]), 0.f);
            o[e] = f2bf(x);
        }
        *reinterpret_cast<u16x8*>(&Xl[r][q * 8]) = o;
    }
#pragma unroll
    for (int i = 0; i < 4; i++) {
        int idx = t + i * 256;
        int r = idx >> 4, q = idx & 15;
        *reinterpret_cast<u16x8*>(&Wt[r][q * 8]) =
            *reinterpret_cast<const u16x8*>(&WtG[r * 128 + q * 8]);
    }
    __syncthreads();

    int lane = t & 63, w = t >> 6;
    int wr = w * 32;
    int fr = lane & 15;
    int fs = (lane >> 4) * 8;
    f32x4 acc[2][4] = {};
#pragma unroll
    for (int ks = 0; ks < 4; ks++) {
        bf16x8 a[2], b[4];
#pragma unroll
        for (int m = 0; m < 2; m++)
            a[m] = *reinterpret_cast<const bf16x8*>(&Xl[wr + m * 16 + fr][ks * 32 + fs]);
#pragma unroll
        for (int c = 0; c < 4; c++)
            b[c] = *reinterpret_cast<const bf16x8*>(&Wt[c * 16 + fr][ks * 32 + fs]);
#pragma unroll
        for (int m = 0; m < 2; m++)
#pragma unroll
            for (int c = 0; c < 4; c++)
                acc[m][c] = __builtin_amdgcn_mfma_f32_16x16x32_bf16(a[m], b[c], acc[m][c], 0, 0, 0);
    }

    int crow = (lane >> 4) * 4, ccol = lane & 15;
#pragma unroll
    for (int m = 0; m < 2; m++) {
#pragma unroll
        for (int c = 0; c < 3; c++) {
#pragma unroll
            for (int rg = 0; rg < 4; rg++) {
                int grow = row0 + wr + m * 16 + crow + rg;
                int gcol = c * 16 + ccol;
                if (grow < n && gcol < 40)
                    Y[(size_t)grow * 64 + gcol] = f2bf(acc[m][c][rg]);
            }
        }
    }
}

// ---------------- CSR gather 128, FEATURE-SPLIT by XCD half ----------------
// grid 6256: xcd=bid&7, half=xcd>>2 (features half*64..), grp=(bid>>3)*4+(bid&3).
// Each block: 32 nodes x half-row. Lanes 0-31 = node A, 32-63 = node B.
// Inactive-source shfl lanes hold idx=0/dv=0, so ragged windows auto-zero.
__global__ __launch_bounds__(256) void k_gather128h(const u32* __restrict__ xwb,
                                                    u32* __restrict__ aggb,
                                                    const u32* __restrict__ rsd,
                                                    const int* __restrict__ csr,
                                                    const float* __restrict__ dinv,
                                                    float* __restrict__ stats) {
    __shared__ float red[256];
    __shared__ float red2[256];
    int t = threadIdx.x;
    int w = t >> 6, l = t & 63;
    int lc = l & 31;
    int sub = l >> 5;             // 0 = node A, 1 = node B
    int bid = blockIdx.x;
    int xcd = bid & 7;
    int half = xcd >> 2;
    int grp = (bid >> 3) * 4 + (xcd & 3);
    if (grp >= (NN + 31) / 32) return;
    int fbase = half * 32;        // u32 offset into 64-u32 row

    float sx = 0.f, sy = 0.f, sxx = 0.f, syy = 0.f;
    for (int it = 0; it < 4; it++) {
        int node = grp * 32 + w * 8 + it * 2 + sub;   // < NN (grp < 3125)
        float dd = dinv[node];
        u32 us = xwb[(size_t)node * 64 + fbase + lc];
        float ax = dd * dd * bf_lo(us);
        float ay = dd * dd * bf_hi(us);
        u32 rs = rsd[node];
        int p = (int)(rs >> 8);
        int pe = p + (int)(rs & 255u);
        int sbase = l & 32;
        while (true) {
            int rem = pe - p;
            int cnt = rem > 32 ? 32 : (rem > 0 ? rem : 0);
            if (!__any(cnt > 0)) break;
            int myidx = 0;
            float mydv = 0.f;
            if (lc < cnt) {
                myidx = csr[p + lc];
                mydv  = dd * dinv[myidx];
            }
            int cmax = cnt;
            int co = __shfl(cnt, l ^ 32);
            if (co > cmax) cmax = co;
            int j = 0;
            for (; j + 4 <= cmax; j += 4) {
                int s0 = __shfl(myidx, sbase + j);
                int s1 = __shfl(myidx, sbase + j + 1);
                int s2 = __shfl(myidx, sbase + j + 2);
                int s3 = __shfl(myidx, sbase + j + 3);
                float c0 = __shfl(mydv, sbase + j);
                float c1 = __shfl(mydv, sbase + j + 1);
                float c2 = __shfl(mydv, sbase + j + 2);
                float c3 = __shfl(mydv, sbase + j + 3);
                u32 u0 = xwb[(size_t)s0 * 64 + fbase + lc];
                u32 u1 = xwb[(size_t)s1 * 64 + fbase + lc];
                u32 u2 = xwb[(size_t)s2 * 64 + fbase + lc];
                u32 u3 = xwb[(size_t)s3 * 64 + fbase + lc];
                ax += c0 * bf_lo(u0) + c1 * bf_lo(u1) + c2 * bf_lo(u2) + c3 * bf_lo(u3);
                ay += c0 * bf_hi(u0) + c1 * bf_hi(u1) + c2 * bf_hi(u2) + c3 * bf_hi(u3);
            }
            for (; j < cmax; j++) {
                int s = __shfl(myidx, sbase + j);
                float c = __shfl(mydv, sbase + j);
                u32 u = xwb[(size_t)s * 64 + fbase + lc];
                ax += c * bf_lo(u);
                ay += c * bf_hi(u);
            }
            p += cnt;
        }
        aggb[(size_t)node * 64 + fbase + lc] = (u32)f2bf(ax) | ((u32)f2bf(ay) << 16);
        sx += ax; sxx += ax * ax;
        sy += ay; syy += ay * ay;
    }
    // fold node-B lanes into node-A lanes (same features)
    sx  += __shfl_xor(sx, 32);
    sy  += __shfl_xor(sy, 32);
    sxx += __shfl_xor(sxx, 32);
    syy += __shfl_xor(syy, 32);
    if (l < 32) {
        red[w * 64 + lc * 2]      = sx;
        red[w * 64 + lc * 2 + 1]  = sy;
        red2[w * 64 + lc * 2]     = sxx;
        red2[w * 64 + lc * 2 + 1] = syy;
    }
    __syncthreads();
    if (t < 64) {
        float s  = red[t] + red[64 + t] + red[128 + t] + red[192 + t];
        float s2 = red2[t] + red2[64 + t] + red2[128 + t] + red2[192 + t];
        atomicAdd(&stats[half * 64 + t], s);
        atomicAdd(&stats[128 + half * 64 + t], s2);
    }
}

// ---------------- CSR gather 40 (bf16, rows padded to 64) + bias + log_softmax ----------------
__global__ __launch_bounds__(256) void k_gather40_lsm(const u16* __restrict__ xwb,
                                                      const float* __restrict__ b2,
                                                      float* __restrict__ out,
                                                      const u32* __restrict__ rsd,
                                                      const int* __restrict__ csr,
                                                      const float* __restrict__ dinv) {
    int node = blockIdx.x * 4 + (threadIdx.x >> 6);
    if (node >= NN) return;
    int lane = threadIdx.x & 63;
    float dd = dinv[node];
    float acc = 0.f;
    if (lane < 40) acc = dd * dd * __uint_as_float((u32)xwb[(size_t)node * 64 + lane] << 16);
    u32 rs = rsd[node];
    int p = (int)(rs >> 8);
    int pe = p + (int)(rs & 255u);
    while (p < pe) {
        int cnt = pe - p;
        if (cnt > 64) cnt = 64;
        int myidx = 0;
        float mydv = 0.f;
        if (lane < cnt) {
            myidx = csr[p + lane];
            mydv  = dd * dinv[myidx];
        }
        int j = 0;
        for (; j + 2 <= cnt; j += 2) {
            int sA = __shfl(myidx, j);
            int sB = __shfl(myidx, j + 1);
            float cA = __shfl(mydv, j);
            float cB = __shfl(mydv, j + 1);
            float vA = 0.f, vB = 0.f;
            if (lane < 40) {
                vA = __uint_as_float((u32)xwb[(size_t)sA * 64 + lane] << 16);
                vB = __uint_as_float((u32)xwb[(size_t)sB * 64 + lane] << 16);
            }
            acc += cA * vA + cB * vB;
        }
        if (j < cnt) {
            int s = __shfl(myidx, j);
            float c = __shfl(mydv, j);
            if (lane < 40) acc += c * __uint_as_float((u32)xwb[(size_t)s * 64 + lane] << 16);
        }
        p += cnt;
    }
    float v = (lane < 40) ? acc + b2[lane] : -1e30f;
    float m = v;
#pragma unroll
    for (int o = 32; o; o >>= 1) m = fmaxf(m, __shfl_xor(m, o));
    float ex = (lane < 40) ? expf(v - m) : 0.f;
    float sum = ex;
#pragma unroll
    for (int o = 32; o; o >>= 1) sum += __shfl_xor(sum, o);
    if (lane < 40) out[(size_t)node * 40 + lane] = v - m - logf(sum);
}

// ---------------- launcher ----------------
extern "C" void kernel_launch(void* const* d_in, const int* in_sizes, int n_in,
                              void* d_out, int out_size, void* d_ws, size_t ws_size,
                              hipStream_t stream) {
    const float* x  = (const float*)d_in[0];
    const int* ei   = (const int*)d_in[1];
    const int* src  = ei;
    const int* dst  = ei + NE;
    const float* W0 = (const float*)d_in[2];
    const float* g0 = (const float*)d_in[4];
    const float* be0= (const float*)d_in[5];
    const float* W1 = (const float*)d_in[6];
    const float* g1 = (const float*)d_in[8];
    const float* be1= (const float*)d_in[9];
    const float* W2 = (const float*)d_in[10];
    const float* b2 = (const float*)d_in[11];
    float* out = (float*)d_out;

    // workspace layout (4-byte words) — identical to R14
    float* ws      = (float*)d_ws;
    float* dinv    = ws;
    float* stats0  = ws + 100000;
    float* stats1  = ws + 100256;
    int* gcur      = (int*)(ws + 100512);
    u32* rsd       = (u32*)(ws + 100912);
    u16* wt0       = (u16*)(ws + 200912);
    u16* wt1       = (u16*)(ws + 209104);
    u16* wt2       = (u16*)(ws + 217296);
    u32* bkt       = (u32*)(ws + 221392);
    int* csr       = (int*)(ws + 2123216);
    u16* bufA16    = (u16*)(ws + 4025040);
    u32* bufB      = (u32*)(ws + 10425040);

    // ---- prep: zero counters, transpose weights, build bucketed CSR ----
    k_zero_ints<<<4, 256, 0, stream>>>((int*)stats0, 903);   // stats0+stats1+gcur
    k_prept<<<24, 256, 0, stream>>>(W0, W1, W2, wt0, wt1, wt2);
    k_bscatter<<<(NE + CHA - 1) / CHA, 256, 0, stream>>>(src, dst, gcur, bkt);
    k_csr<<<NB, BKN, 0, stream>>>(bkt, gcur, rsd, csr, dinv);

    int gm = (NN + 127) / 128;   // 782 MFMA gemm blocks
    int gh = 782 * 8;            // 6256 feature-split gather blocks (two halves x 3128 grps)

    // ---- layer 0 ----
    k_gemm128m_f0<<<gm, 256, 0, stream>>>(x, wt0, bufA16, NN);
    k_gather128h<<<gh, 256, 0, stream>>>((const u32*)bufA16, bufB, rsd, csr, dinv, stats0);

    // ---- layer 1 (BN0+ReLU fused into GEMM X-staging, bf16-packed agg input) ----
    k_gemm128m_b1<<<gm, 256, 0, stream>>>(bufB, wt1, bufA16, NN, stats0, g0, be0);
    k_gather128h<<<gh, 256, 0, stream>>>((const u32*)bufA16, bufB, rsd, csr, dinv, stats1);

    // ---- layer 2 (BN1+ReLU fused into GEMM; gather + bias + log_softmax fused) ----
    k_gemm40m<<<gm, 256, 0, stream>>>(bufB, wt2, bufA16, NN, stats1, g1, be1);
    k_gather40_lsm<<<(NN + 3) / 4, 256, 0, stream>>>(bufA16, b2, out, rsd, csr, dinv);
}

// Round 16
// 468.838 us; speedup vs baseline: 1.0212x; 1.0212x over previous
//
#include <hip/hip_runtime.h>
#include <math.h>

#define NN 100000
#define NE 1600000
#define EPSF 1e-5f
#define NB 391          // buckets of 256 nodes
#define BKN 256
#define CAP 4864        // fixed bucket capacity (mean 4092, sigma 64 -> +12 sigma)
#define CHA 4096        // edges per block in bucket scatter

typedef unsigned short u16;
typedef unsigned int u32;
typedef __attribute__((ext_vector_type(8))) short bf16x8;   // MFMA A/B frag (4 VGPRs)
typedef __attribute__((ext_vector_type(4))) float f32x4;    // MFMA C/D frag
typedef __attribute__((ext_vector_type(8))) unsigned short u16x8;

__device__ __forceinline__ u16 f2bf(float f) {
    u32 u = __float_as_uint(f);
    u32 r = (u + 0x7fffu + ((u >> 16) & 1u)) >> 16;   // RNE
    return (u16)r;
}
__device__ __forceinline__ float bf_lo(u32 u) { return __uint_as_float(u << 16); }
__device__ __forceinline__ float bf_hi(u32 u) { return __uint_as_float(u & 0xffff0000u); }

// ---------------- misc ----------------
__global__ void k_zero_ints(int* p, int n) {
    int i = blockIdx.x * 256 + threadIdx.x;
    if (i < n) p[i] = 0;
}

// ---------------- weight pre-transpose: Wt[c][k] bf16 (once per launch) ----------------
__global__ __launch_bounds__(256) void k_prept(const float* __restrict__ W0,
                                               const float* __restrict__ W1,
                                               const float* __restrict__ W2,
                                               u16* __restrict__ wt0,
                                               u16* __restrict__ wt1,
                                               u16* __restrict__ wt2) {
    int b = blockIdx.x, t = threadIdx.x;
    if (b < 8) {
        for (int idx = t; idx < 16 * 128; idx += 256) {
            int k = b * 16 + (idx >> 7), c = idx & 127;
            wt0[c * 128 + k] = f2bf(W0[k * 128 + c]);
        }
    } else if (b < 16) {
        for (int idx = t; idx < 16 * 128; idx += 256) {
            int k = (b - 8) * 16 + (idx >> 7), c = idx & 127;
            wt1[c * 128 + k] = f2bf(W1[k * 128 + c]);
        }
    } else {
        for (int idx = t; idx < 16 * 64; idx += 256) {
            int k = (b - 16) * 16 + (idx >> 6), c = idx & 63;
            wt2[c * 128 + k] = f2bf(c < 40 ? W2[k * 40 + c] : 0.f);
        }
    }
}

// ---------------- CSR build pass A: scatter edges into fixed-capacity buckets ----------------
__global__ __launch_bounds__(256) void k_bscatter(const int* __restrict__ src,
                                                  const int* __restrict__ dst,
                                                  int* __restrict__ gcur,
                                                  u32* __restrict__ bkt) {
    __shared__ int hist[NB];
    __shared__ int base[NB];
    int t = threadIdx.x;
    long e0 = (long)blockIdx.x * CHA;
    for (int i = t; i < NB; i += 256) hist[i] = 0;
    __syncthreads();
#pragma unroll
    for (int i = 0; i < CHA / 256; i++) {
        long e = e0 + i * 256 + t;
        if (e < NE) atomicAdd(&hist[dst[e] >> 8], 1);
    }
    __syncthreads();
    for (int i = t; i < NB; i += 256)
        base[i] = i * CAP + atomicAdd(&gcur[i], hist[i]);
    __syncthreads();
    for (int i = t; i < NB; i += 256) hist[i] = 0;
    __syncthreads();
#pragma unroll
    for (int i = 0; i < CHA / 256; i++) {
        long e = e0 + i * 256 + t;
        if (e < NE) {
            int d = dst[e];
            int s = src[e];
            int b = d >> 8;
            int r = atomicAdd(&hist[b], 1);
            bkt[base[b] + r] = (u32)s | ((u32)(d & 255) << 17);
        }
    }
}

// ---------------- CSR build pass B (per-bucket hist+scan+fill; rsd=(start<<8)|deg; dinv) ----------------
__global__ __launch_bounds__(BKN) void k_csr(const u32* __restrict__ bkt,
                                             const int* __restrict__ gcur,
                                             u32* __restrict__ rsd,
                                             int* __restrict__ csr,
                                             float* __restrict__ dinv) {
    __shared__ int cnt[BKN];
    __shared__ int tmp[BKN];
    __shared__ int cur[BKN];
    int t = threadIdx.x, b = blockIdx.x;
    int ebase = b * CAP;
    int m = gcur[b];
    cnt[t] = 0;
    __syncthreads();
    for (int i = t; i < m; i += BKN)
        atomicAdd(&cnt[(bkt[ebase + i] >> 17) & 255], 1);
    __syncthreads();
    int v = cnt[t];
    tmp[t] = v;
    __syncthreads();
    for (int o = 1; o < BKN; o <<= 1) {
        int u = (t >= o) ? tmp[t - o] : 0;
        __syncthreads();
        tmp[t] += u;
        __syncthreads();
    }
    int excl = tmp[t] - v;
    int node = b * BKN + t;
    if (node < NN) {
        rsd[node] = ((u32)(ebase + excl) << 8) | (u32)v;
        dinv[node] = rsqrtf((float)(v + 1));
    }
    cur[t] = ebase + excl;
    __syncthreads();
    for (int i = t; i < m; i += BKN) {
        u32 p = bkt[ebase + i];
        int pos = atomicAdd(&cur[(p >> 17) & 255], 1);
        csr[pos] = (int)(p & 0x1FFFFu);
    }
}

// ---------------- MFMA GEMM (layer0): fp32 X [n,128] @ Wt -> bf16 [n,128] ----------------
__global__ __launch_bounds__(256) void k_gemm128m_f0(const float* __restrict__ X,
                                                     const u16* __restrict__ WtG,
                                                     u16* __restrict__ Y, int n) {
    __shared__ u16 Xl[128][136];   // +8 pad
    __shared__ u16 Wt[128][136];   // Wt[col][k]
    int t = threadIdx.x;
    int row0 = blockIdx.x * 128;

#pragma unroll
    for (int i = 0; i < 16; i++) {
        int idx = t + i * 256;
        int r = idx >> 5, q = idx & 31;
        int gr = row0 + r;
        float4 v = make_float4(0.f, 0.f, 0.f, 0.f);
        if (gr < n) v = reinterpret_cast<const float4*>(X + (size_t)gr * 128)[q];
        ushort4 o;
        o.x = f2bf(v.x); o.y = f2bf(v.y); o.z = f2bf(v.z); o.w = f2bf(v.w);
        *reinterpret_cast<ushort4*>(&Xl[r][q * 4]) = o;
    }
#pragma unroll
    for (int i = 0; i < 8; i++) {
        int idx = t + i * 256;    // 2048 chunks of 8 u16
        int r = idx >> 4, q = idx & 15;
        *reinterpret_cast<u16x8*>(&Wt[r][q * 8]) =
            *reinterpret_cast<const u16x8*>(&WtG[r * 128 + q * 8]);
    }
    __syncthreads();

    int lane = t & 63, w = t >> 6;
    int wr = (w >> 1) * 64, wc = (w & 1) * 64;
    int fr = lane & 15;
    int fs = (lane >> 4) * 8;
    f32x4 acc[4][4] = {};
#pragma unroll
    for (int ks = 0; ks < 4; ks++) {
        bf16x8 a[4], b[4];
#pragma unroll
        for (int m = 0; m < 4; m++)
            a[m] = *reinterpret_cast<const bf16x8*>(&Xl[wr + m * 16 + fr][ks * 32 + fs]);
#pragma unroll
        for (int c = 0; c < 4; c++)
            b[c] = *reinterpret_cast<const bf16x8*>(&Wt[wc + c * 16 + fr][ks * 32 + fs]);
#pragma unroll
        for (int m = 0; m < 4; m++)
#pragma unroll
            for (int c = 0; c < 4; c++)
                acc[m][c] = __builtin_amdgcn_mfma_f32_16x16x32_bf16(a[m], b[c], acc[m][c], 0, 0, 0);
    }

    int crow = (lane >> 4) * 4, ccol = lane & 15;
#pragma unroll
    for (int m = 0; m < 4; m++) {
#pragma unroll
        for (int c = 0; c < 4; c++) {
#pragma unroll
            for (int rg = 0; rg < 4; rg++) {
                int grow = row0 + wr + m * 16 + crow + rg;
                if (grow < n)
                    Y[(size_t)grow * 128 + wc + c * 16 + ccol] = f2bf(acc[m][c][rg]);
            }
        }
    }
}

// ---------------- MFMA GEMM (layer1): bf16-packed X + fused BN+ReLU -> bf16 [n,128] ----------------
__global__ __launch_bounds__(256) void k_gemm128m_b1(const u32* __restrict__ Xb,
                                                     const u16* __restrict__ WtG,
                                                     u16* __restrict__ Y, int n,
                                                     const float* __restrict__ stats,
                                                     const float* __restrict__ g,
                                                     const float* __restrict__ be) {
    __shared__ u16 Xl[128][136];
    __shared__ u16 Wt[128][136];
    __shared__ float ssc[128], ssh[128];
    int t = threadIdx.x;
    int row0 = blockIdx.x * 128;

    if (t < 128) {
        float mu = stats[t] * (1.0f / NN);
        float var = stats[128 + t] * (1.0f / NN) - mu * mu;
        float sc = rsqrtf(var + EPSF) * g[t];
        ssc[t] = sc;
        ssh[t] = be[t] - mu * sc;
    }
    __syncthreads();

#pragma unroll
    for (int i = 0; i < 8; i++) {
        int idx = t + i * 256;
        int r = idx >> 4, q = idx & 15;
        int gr = row0 + r;
        uint4 vv = make_uint4(0u, 0u, 0u, 0u);
        if (gr < n) vv = reinterpret_cast<const uint4*>(Xb + (size_t)gr * 64)[q];
        float f[8] = { bf_lo(vv.x), bf_hi(vv.x), bf_lo(vv.y), bf_hi(vv.y),
                       bf_lo(vv.z), bf_hi(vv.z), bf_lo(vv.w), bf_hi(vv.w) };
        u16x8 o;
#pragma unroll
        for (int e = 0; e < 8; e++) {
            int fi = q * 8 + e;
            float x = fmaxf(fmaf(f[e], ssc[fi], ssh[fi]), 0.f);
            o[e] = f2bf(x);
        }
        *reinterpret_cast<u16x8*>(&Xl[r][q * 8]) = o;
    }
#pragma unroll
    for (int i = 0; i < 8; i++) {
        int idx = t + i * 256;
        int r = idx >> 4, q = idx & 15;
        *reinterpret_cast<u16x8*>(&Wt[r][q * 8]) =
            *reinterpret_cast<const u16x8*>(&WtG[r * 128 + q * 8]);
    }
    __syncthreads();

    int lane = t & 63, w = t >> 6;
    int wr = (w >> 1) * 64, wc = (w & 1) * 64;
    int fr = lane & 15;
    int fs = (lane >> 4) * 8;
    f32x4 acc[4][4] = {};
#pragma unroll
    for (int ks = 0; ks < 4; ks++) {
        bf16x8 a[4], b[4];
#pragma unroll
        for (int m = 0; m < 4; m++)
            a[m] = *reinterpret_cast<const bf16x8*>(&Xl[wr + m * 16 + fr][ks * 32 + fs]);
#pragma unroll
        for (int c = 0; c < 4; c++)
            b[c] = *reinterpret_cast<const bf16x8*>(&Wt[wc + c * 16 + fr][ks * 32 + fs]);
#pragma unroll
        for (int m = 0; m < 4; m++)
#pragma unroll
            for (int c = 0; c < 4; c++)
                acc[m][c] = __builtin_amdgcn_mfma_f32_16x16x32_bf16(a[m], b[c], acc[m][c], 0, 0, 0);
    }

    int crow = (lane >> 4) * 4, ccol = lane & 15;
#pragma unroll
    for (int m = 0; m < 4; m++) {
#pragma unroll
        for (int c = 0; c < 4; c++) {
#pragma unroll
            for (int rg = 0; rg < 4; rg++) {
                int grow = row0 + wr + m * 16 + crow + rg;
                if (grow < n)
                    Y[(size_t)grow * 128 + wc + c * 16 + ccol] = f2bf(acc[m][c][rg]);
            }
        }
    }
}

// ---------------- MFMA GEMM (layer2): bf16-packed X + BN+ReLU -> bf16 [n,64] (40 valid) ----------------
__global__ __launch_bounds__(256) void k_gemm40m(const u32* __restrict__ Xb,
                                                 const u16* __restrict__ WtG,
                                                 u16* __restrict__ Y, int n,
                                                 const float* __restrict__ stats,
                                                 const float* __restrict__ g,
                                                 const float* __restrict__ be) {
    __shared__ u16 Xl[128][136];
    __shared__ u16 Wt[64][136];
    __shared__ float ssc[128], ssh[128];
    int t = threadIdx.x;
    int row0 = blockIdx.x * 128;

    if (t < 128) {
        float mu = stats[t] * (1.0f / NN);
        float var = stats[128 + t] * (1.0f / NN) - mu * mu;
        float sc = rsqrtf(var + EPSF) * g[t];
        ssc[t] = sc;
        ssh[t] = be[t] - mu * sc;
    }
    __syncthreads();

#pragma unroll
    for (int i = 0; i < 8; i++) {
        int idx = t + i * 256;
        int r = idx >> 4, q = idx & 15;
        int gr = row0 + r;
        uint4 vv = make_uint4(0u, 0u, 0u, 0u);
        if (gr < n) vv = reinterpret_cast<const uint4*>(Xb + (size_t)gr * 64)[q];
        float f[8] = { bf_lo(vv.x), bf_hi(vv.x), bf_lo(vv.y), bf_hi(vv.y),
                       bf_lo(vv.z), bf_hi(vv.z), bf_lo(vv.w), bf_hi(vv.w) };
        u16x8 o;
#pragma unroll
        for (int e = 0; e < 8; e++) {
            int fi = q * 8 + e;
            float x = fmaxf(fmaf(f[e], ssc[fi], ssh[fi]), 0.f);
            o[e] = f2bf(x);
        }
        *reinterpret_cast<u16x8*>(&Xl[r][q * 8]) = o;
    }
#pragma unroll
    for (int i = 0; i < 4; i++) {
        int idx = t + i * 256;   // 1024 chunks = 64 rows x 16
        int r = idx >> 4, q = idx & 15;
        *reinterpret_cast<u16x8*>(&Wt[r][q * 8]) =
            *reinterpret_cast<const u16x8*>(&WtG[r * 128 + q * 8]);
    }
    __syncthreads();

    int lane = t & 63, w = t >> 6;
    int wr = w * 32;
    int fr = lane & 15;
    int fs = (lane >> 4) * 8;
    f32x4 acc[2][4] = {};
#pragma unroll
    for (int ks = 0; ks < 4; ks++) {
        bf16x8 a[2], b[4];
#pragma unroll
        for (int m = 0; m < 2; m++)
            a[m] = *reinterpret_cast<const bf16x8*>(&Xl[wr + m * 16 + fr][ks * 32 + fs]);
#pragma unroll
        for (int c = 0; c < 4; c++)
            b[c] = *reinterpret_cast<const bf16x8*>(&Wt[c * 16 + fr][ks * 32 + fs]);
#pragma unroll
        for (int m = 0; m < 2; m++)
#pragma unroll
            for (int c = 0; c < 4; c++)
                acc[m][c] = __builtin_amdgcn_mfma_f32_16x16x32_bf16(a[m], b[c], acc[m][c], 0, 0, 0);
    }

    int crow = (lane >> 4) * 4, ccol = lane & 15;
#pragma unroll
    for (int m = 0; m < 2; m++) {
#pragma unroll
        for (int c = 0; c < 3; c++) {          // cols 0..47 (40 valid)
#pragma unroll
            for (int rg = 0; rg < 4; rg++) {
                int grow = row0 + wr + m * 16 + crow + rg;
                int gcol = c * 16 + ccol;
                if (grow < n && gcol < 40)
                    Y[(size_t)grow * 64 + gcol] = f2bf(acc[m][c][rg]);
            }
        }
    }
}

// ---------------- CSR gather 128 bf16 -> packed-bf16 agg + fused BN stats ----------------
__global__ __launch_bounds__(256) void k_gather128s(const u32* __restrict__ xwb,
                                                    u32* __restrict__ aggb,
                                                    const u32* __restrict__ rsd,
                                                    const int* __restrict__ csr,
                                                    const float* __restrict__ dinv,
                                                    float* __restrict__ stats) {
    __shared__ float red[1024];
    int t = threadIdx.x;
    int w = t >> 6, l = t & 63;
    int nb = blockIdx.x * 32 + w * 8;
    float sx = 0.f, sy = 0.f, sxx = 0.f, syy = 0.f;
    for (int i = 0; i < 8; i++) {
        int node = nb + i;
        if (node >= NN) break;
        float dd = dinv[node];
        u32 us = xwb[(size_t)node * 64 + l];
        float ax = dd * dd * bf_lo(us);
        float ay = dd * dd * bf_hi(us);
        u32 rs = rsd[node];
        int p = (int)(rs >> 8);
        int pe = p + (int)(rs & 255u);
        while (p < pe) {
            int cnt = pe - p;
            if (cnt > 64) cnt = 64;
            int myidx = 0;
            float mydv = 0.f;
            if (l < cnt) {
                myidx = csr[p + l];
                mydv  = dd * dinv[myidx];
            }
            int j = 0;
            for (; j + 4 <= cnt; j += 4) {
                int s0 = __shfl(myidx, j);
                int s1 = __shfl(myidx, j + 1);
                int s2 = __shfl(myidx, j + 2);
                int s3 = __shfl(myidx, j + 3);
                float c0 = __shfl(mydv, j);
                float c1 = __shfl(mydv, j + 1);
                float c2 = __shfl(mydv, j + 2);
                float c3 = __shfl(mydv, j + 3);
                u32 u0 = xwb[(size_t)s0 * 64 + l];
                u32 u1 = xwb[(size_t)s1 * 64 + l];
                u32 u2 = xwb[(size_t)s2 * 64 + l];
                u32 u3 = xwb[(size_t)s3 * 64 + l];
                ax += c0 * bf_lo(u0) + c1 * bf_lo(u1) + c2 * bf_lo(u2) + c3 * bf_lo(u3);
                ay += c0 * bf_hi(u0) + c1 * bf_hi(u1) + c2 * bf_hi(u2) + c3 * bf_hi(u3);
            }
            for (; j < cnt; j++) {
                int s = __shfl(myidx, j);
                float c = __shfl(mydv, j);
                u32 u = xwb[(size_t)s * 64 + l];
                ax += c * bf_lo(u);
                ay += c * bf_hi(u);
            }
            p += cnt;
        }
        aggb[(size_t)node * 64 + l] = (u32)f2bf(ax) | ((u32)f2bf(ay) << 16);
        sx += ax; sxx += ax * ax;
        sy += ay; syy += ay * ay;
    }
    red[w * 128 + 2 * l]     = sx;
    red[w * 128 + 2 * l + 1] = sy;
    red[512 + w * 128 + 2 * l]     = sxx;
    red[512 + w * 128 + 2 * l + 1] = syy;
    __syncthreads();
    if (t < 128) {
        float s  = red[t] + red[128 + t] + red[256 + t] + red[384 + t];
        float s2 = red[512 + t] + red[640 + t] + red[768 + t] + red[896 + t];
        atomicAdd(&stats[t], s);
        atomicAdd(&stats[128 + t], s2);
    }
}

// ---------------- CSR gather 40 (bf16, rows padded to 64) + bias + log_softmax ----------------
__global__ __launch_bounds__(256) void k_gather40_lsm(const u16* __restrict__ xwb,
                                                      const float* __restrict__ b2,
                                                      float* __restrict__ out,
                                                      const u32* __restrict__ rsd,
                                                      const int* __restrict__ csr,
                                                      const float* __restrict__ dinv) {
    int node = blockIdx.x * 4 + (threadIdx.x >> 6);
    if (node >= NN) return;
    int lane = threadIdx.x & 63;
    float dd = dinv[node];
    float acc = 0.f;
    if (lane < 40) acc = dd * dd * __uint_as_float((u32)xwb[(size_t)node * 64 + lane] << 16);
    u32 rs = rsd[node];
    int p = (int)(rs >> 8);
    int pe = p + (int)(rs & 255u);
    while (p < pe) {
        int cnt = pe - p;
        if (cnt > 64) cnt = 64;
        int myidx = 0;
        float mydv = 0.f;
        if (lane < cnt) {
            myidx = csr[p + lane];
            mydv  = dd * dinv[myidx];
        }
        int j = 0;
        for (; j + 2 <= cnt; j += 2) {
            int sA = __shfl(myidx, j);
            int sB = __shfl(myidx, j + 1);
            float cA = __shfl(mydv, j);
            float cB = __shfl(mydv, j + 1);
            float vA = 0.f, vB = 0.f;
            if (lane < 40) {
                vA = __uint_as_float((u32)xwb[(size_t)sA * 64 + lane] << 16);
                vB = __uint_as_float((u32)xwb[(size_t)sB * 64 + lane] << 16);
            }
            acc += cA * vA + cB * vB;
        }
        if (j < cnt) {
            int s = __shfl(myidx, j);
            float c = __shfl(mydv, j);
            if (lane < 40) acc += c * __uint_as_float((u32)xwb[(size_t)s * 64 + lane] << 16);
        }
        p += cnt;
    }
    float v = (lane < 40) ? acc + b2[lane] : -1e30f;
    float m = v;
#pragma unroll
    for (int o = 32; o; o >>= 1) m = fmaxf(m, __shfl_xor(m, o));
    float ex = (lane < 40) ? expf(v - m) : 0.f;
    float sum = ex;
#pragma unroll
    for (int o = 32; o; o >>= 1) sum += __shfl_xor(sum, o);
    if (lane < 40) out[(size_t)node * 40 + lane] = v - m - logf(sum);
}

// ---------------- launcher ----------------
extern "C" void kernel_launch(void* const* d_in, const int* in_sizes, int n_in,
                              void* d_out, int out_size, void* d_ws, size_t ws_size,
                              hipStream_t stream) {
    const float* x  = (const float*)d_in[0];
    const int* ei   = (const int*)d_in[1];
    const int* src  = ei;
    const int* dst  = ei + NE;
    const float* W0 = (const float*)d_in[2];
    const float* g0 = (const float*)d_in[4];
    const float* be0= (const float*)d_in[5];
    const float* W1 = (const float*)d_in[6];
    const float* g1 = (const float*)d_in[8];
    const float* be1= (const float*)d_in[9];
    const float* W2 = (const float*)d_in[10];
    const float* b2 = (const float*)d_in[11];
    float* out = (float*)d_out;

    // workspace layout (4-byte words)
    // dinv    [0,       100,000)
    // stats0  [100,000, 100,256)  } zeroed together with gcur
    // stats1  [100,256, 100,512)  }
    // gcur    [100,512, 100,903)  }
    // rsd     [100,912, 200,912)
    // wt0     [200,912, 209,104)   128x128 u16
    // wt1     [209,104, 217,296)   128x128 u16
    // wt2     [217,296, 221,392)   64x128 u16
    // bkt     [221,392, 2,123,216) NB*CAP
    // csr     [2,123,216, 4,025,040) NB*CAP
    // bufA16  [4,025,040, 10,425,040)  NN*128 u16 (layer2 uses NN*64)
    // bufB    [10,425,040, 13,625,040) NN*64 u32
    float* ws      = (float*)d_ws;
    float* dinv    = ws;
    float* stats0  = ws + 100000;
    float* stats1  = ws + 100256;
    int* gcur      = (int*)(ws + 100512);
    u32* rsd       = (u32*)(ws + 100912);
    u16* wt0       = (u16*)(ws + 200912);
    u16* wt1       = (u16*)(ws + 209104);
    u16* wt2       = (u16*)(ws + 217296);
    u32* bkt       = (u32*)(ws + 221392);
    int* csr       = (int*)(ws + 2123216);
    u16* bufA16    = (u16*)(ws + 4025040);
    u32* bufB      = (u32*)(ws + 10425040);

    // ---- prep: zero counters, transpose weights, build bucketed CSR ----
    k_zero_ints<<<4, 256, 0, stream>>>((int*)stats0, 903);   // stats0+stats1+gcur
    k_prept<<<24, 256, 0, stream>>>(W0, W1, W2, wt0, wt1, wt2);
    k_bscatter<<<(NE + CHA - 1) / CHA, 256, 0, stream>>>(src, dst, gcur, bkt);
    k_csr<<<NB, BKN, 0, stream>>>(bkt, gcur, rsd, csr, dinv);

    int gm = (NN + 127) / 128;   // 782 MFMA gemm blocks
    int gs = (NN + 31) / 32;     // 3125 gather blocks

    // ---- layer 0 ----
    k_gemm128m_f0<<<gm, 256, 0, stream>>>(x, wt0, bufA16, NN);
    k_gather128s<<<gs, 256, 0, stream>>>((const u32*)bufA16, bufB, rsd, csr, dinv, stats0);

    // ---- layer 1 (BN0+ReLU fused into GEMM X-staging, bf16-packed agg input) ----
    k_gemm128m_b1<<<gm, 256, 0, stream>>>(bufB, wt1, bufA16, NN, stats0, g0, be0);
    k_gather128s<<<gs, 256, 0, stream>>>((const u32*)bufA16, bufB, rsd, csr, dinv, stats1);

    // ---- layer 2 (BN1+ReLU fused into GEMM; gather + bias + log_softmax fused) ----
    k_gemm40m<<<gm, 256, 0, stream>>>(bufB, wt2, bufA16, NN, stats1, g1, be1);
    k_gather40_lsm<<<(NN + 3) / 4, 256, 0, stream>>>(bufA16, b2, out, rsd, csr, dinv);
}